// Round 12
// baseline (100.831 us; speedup 1.0000x reference)
//
#include <hip/hip_runtime.h>
#include <math.h>

// Problem constants (from reference)
constexpr int kB = 256, kT = 8, kS = 200, kR = 8, kD = 64, kF = 20;
constexpr int kSP = 224;                     // s padded to 7 K-tiles of 32
constexpr float kW1 = 3.14159265358979323846f / 19.0f;

typedef __attribute__((ext_vector_type(8))) short s16x8;   // 8 bf16 = 4 VGPR
typedef __attribute__((ext_vector_type(4))) float f32x4;

// split-bf16: x = hi + lo + eps, |eps| ~ 2^-16 |x| (validated R9-R11: 3.81e-6)
__device__ __forceinline__ unsigned short bf_hi(float x, float& hf) {
    unsigned u = __float_as_uint(x) & 0xffff0000u;
    hf = __uint_as_float(u);
    return (unsigned short)(u >> 16);
}
__device__ __forceinline__ unsigned short bf_rne(float x) {
    unsigned v = __float_as_uint(x);
    return (unsigned short)((v + 0x7fffu + ((v >> 16) & 1u)) >> 16);
}

// ---------------------------------------------------------------------------
// Kernel 1 (prep) — VERBATIM from R11 (clean attribution: Δtotal = Δmain).
// grid 7*256, one block per (b, 32-row s-slice), 8.45 KB LDS.
// ---------------------------------------------------------------------------
__global__ __launch_bounds__(256) void prep_kernel(
    const float* __restrict__ seq,   // [B,S,D]
    const float* __restrict__ dt,    // [B,S]
    const float* __restrict__ fr,    // [R,F]
    const float* __restrict__ fi,    // [R,F]
    const int*   __restrict__ vm,    // [B,S]
    float* __restrict__ dec,                 // [B,R,S]
    unsigned short* __restrict__ seqH,       // [B,S,D]
    unsigned short* __restrict__ seqL,       // [B,S,D]
    unsigned short* __restrict__ seqTH,      // [B,D,224]
    unsigned short* __restrict__ seqTL)      // [B,D,224]
{
    __shared__ unsigned short lh[32][66], ll[32][66];   // 8.45 KB

    const int o = blockIdx.x, b = o & 255, slice = o >> 8;
    const int s0 = slice * 32;
    const int tid = threadIdx.x;

    // ---- Phase A: split + store [S][D] + LDS stage (2 iters of 256)
    {
        unsigned short* gh = seqH + (size_t)b * kS * kD;
        unsigned short* gl = seqL + (size_t)b * kS * kD;
#pragma unroll
        for (int it = 0; it < 2; ++it) {
            const int idx = tid + it * 256;            // [0,512)
            const int sl = idx >> 4, d0 = (idx & 15) * 4;
            const int s = s0 + sl;
            float4 x = make_float4(0.f, 0.f, 0.f, 0.f);
            if (s < kS)
                x = *(const float4*)(seq + ((size_t)b * kS + s) * kD + d0);
            ushort4 h, lo; float hf;
            h.x = bf_hi(x.x, hf); lo.x = bf_rne(x.x - hf);
            h.y = bf_hi(x.y, hf); lo.y = bf_rne(x.y - hf);
            h.z = bf_hi(x.z, hf); lo.z = bf_rne(x.z - hf);
            h.w = bf_hi(x.w, hf); lo.w = bf_rne(x.w - hf);
            if (s < kS) {
                *(ushort4*)&gh[s * kD + d0] = h;
                *(ushort4*)&gl[s * kD + d0] = lo;
            }
            *(ushort2*)&lh[sl][d0]     = make_ushort2(h.x, h.y);
            *(ushort2*)&lh[sl][d0 + 2] = make_ushort2(h.z, h.w);
            *(ushort2*)&ll[sl][d0]     = make_ushort2(lo.x, lo.y);
            *(ushort2*)&ll[sl][d0 + 2] = make_ushort2(lo.z, lo.w);
        }
    }

    // ---- Phase B: decay for this slice (thread = r*32 + s_local)
    {
        const int r = tid >> 5, sl = tid & 31;
        const int s = s0 + sl;
        if (s < kS) {
            float frr[kF], fir[kF];
            const float4* f4 = (const float4*)(fr + r * kF);
            const float4* g4 = (const float4*)(fi + r * kF);
#pragma unroll
            for (int c = 0; c < 5; ++c) {
                float4 a = f4[c], g = g4[c];
                frr[4*c+0]=a.x; frr[4*c+1]=a.y; frr[4*c+2]=a.z; frr[4*c+3]=a.w;
                fir[4*c+0]=g.x; fir[4*c+1]=g.y; fir[4*c+2]=g.z; fir[4*c+3]=g.w;
            }
            const float tt = dt[b * kS + s];
            const bool valid = vm[b * kS + s] != 0;
            float s1, c1;
            __sincosf(kW1 * tt, &s1, &c1);
            float ck = c1, sk = s1;
            float acc = frr[0] + c1 * frr[1] - s1 * fir[1];
#pragma unroll
            for (int k = 2; k < kF; ++k) {
                float cn = ck * c1 - sk * s1;
                float sn = sk * c1 + ck * s1;
                ck = cn; sk = sn;
                acc += ck * frr[k] - sk * fir[k];
            }
            float v = fminf(fmaxf(acc * (1.0f / (2.0f * kF)), 0.f), 1.f);
            dec[(b * kR + r) * kS + s] = valid ? v : 0.f;
        }
    }
    __syncthreads();

    // ---- Phase C: transpose-write seqT planes (8 iters of 256)
    {
        unsigned short* th = seqTH + (size_t)b * kD * kSP + s0;
        unsigned short* tl = seqTL + (size_t)b * kD * kSP + s0;
#pragma unroll
        for (int it = 0; it < 8; ++it) {
            const int idx = tid + it * 256;            // [0,2048)
            const int d = idx >> 5, sl = idx & 31;
            th[(size_t)d * kSP + sl] = lh[sl][d];
            tl[(size_t)d * kSP + sl] = ll[sl][d];
        }
    }
}

// ---------------------------------------------------------------------------
// Kernel 2 (main, R12 restructure for load-latency hiding; math identical):
//   GEMM1: wave w owns CONTIGUOUS Mt = 4w..4w+3, fully unrolled; all 16
//          A-frag global loads issued up front; 4 independent acc chains.
//          (R11's strided `Mt += 4` runtime loop serialized load->MFMA->store.)
//   GEMM2 preload: Kt 0..3 B-frags issued BEFORE the softmax barrier, so
//          softmax (~800cy) hides their L2 latency; Kt 4..6 issued at GEMM2
//          entry overlapping Kt 0..3 MFMAs.
//   attr widened to [16][260] for the 16-Mt pad (cols >=200 garbage, masked).
// ---------------------------------------------------------------------------
__global__ __launch_bounds__(256) void rda_mfma(
    const float* __restrict__ target, // [B,T,D]
    const float* __restrict__ tv,     // [B,T,R,D]
    const int*   __restrict__ vm,     // [B,S]
    const float* __restrict__ rel,    // [R,D]
    const float* __restrict__ dec,    // [B,R,S]
    const unsigned short* __restrict__ seqH,   // [B,S,D]
    const unsigned short* __restrict__ seqL,   // [B,S,D]
    const unsigned short* __restrict__ seqTH,  // [B,D,224]
    const unsigned short* __restrict__ seqTL,  // [B,D,224]
    float* __restrict__ out)          // [B,T,R,D]
{
    __shared__ unsigned short riBh[16][72], riBl[16][72];  // 4.5 KB
    __shared__ float attr[16][260];                        // 16.6 KB
    __shared__ unsigned short ath[16][232], atl[16][232];  // 14.5 KB

    const int o = blockIdx.x, b = o & 255, g = o >> 8, t0 = 2 * g;
    const int tid = threadIdx.x, w = tid >> 6, l = tid & 63;
    const int lm = l & 15, lq = l >> 4;

    // ---- P0: riB
    {
        const int n = tid >> 4, d0 = (tid & 15) * 4;
        const int tl_ = n >> 3, r = n & 7;
        const int btl = b * kT + t0 + tl_;
        float4 rv  = *(const float4*)(rel + r * kD + d0);
        float4 tvv = *(const float4*)(tv + ((size_t)btl * kR + r) * kD + d0);
        float4 tg  = *(const float4*)(target + (size_t)btl * kD + d0);
        float x[4] = {(rv.x+tvv.x)*tg.x, (rv.y+tvv.y)*tg.y,
                      (rv.z+tvv.z)*tg.z, (rv.w+tvv.w)*tg.w};
        ushort4 h, lo; float hf;
        h.x = bf_hi(x[0], hf); lo.x = bf_rne(x[0] - hf);
        h.y = bf_hi(x[1], hf); lo.y = bf_rne(x[1] - hf);
        h.z = bf_hi(x[2], hf); lo.z = bf_rne(x[2] - hf);
        h.w = bf_hi(x[3], hf); lo.w = bf_rne(x[3] - hf);
        *(ushort4*)&riBh[n][d0] = h;
        *(ushort4*)&riBl[n][d0] = lo;
    }
    __syncthreads();

    // ---- GEMM1: scores. Wave w: Mt = 4w..4w+3, all loads up front.
    {
        const int MtB = 4 * w;
        s16x8 ah[4][2], al[4][2];
#pragma unroll
        for (int q = 0; q < 4; ++q) {
            const int srow = min((MtB + q) * 16 + lm, kS - 1);  // pad rows clamped (masked later)
            const unsigned short* ph = seqH + ((size_t)b * kS + srow) * kD;
            const unsigned short* pl = seqL + ((size_t)b * kS + srow) * kD;
#pragma unroll
            for (int Kt = 0; Kt < 2; ++Kt) {
                ah[q][Kt] = *(const s16x8*)&ph[Kt * 32 + lq * 8];
                al[q][Kt] = *(const s16x8*)&pl[Kt * 32 + lq * 8];
            }
        }
        s16x8 bh[2], bl[2];
#pragma unroll
        for (int Kt = 0; Kt < 2; ++Kt) {
            bh[Kt] = *(const s16x8*)&riBh[lm][Kt * 32 + lq * 8];
            bl[Kt] = *(const s16x8*)&riBl[lm][Kt * 32 + lq * 8];
        }
        f32x4 acc[4];
#pragma unroll
        for (int q = 0; q < 4; ++q) acc[q] = (f32x4){0.f, 0.f, 0.f, 0.f};
#pragma unroll
        for (int q = 0; q < 4; ++q)
#pragma unroll
            for (int Kt = 0; Kt < 2; ++Kt) {
                acc[q] = __builtin_amdgcn_mfma_f32_16x16x32_bf16(ah[q][Kt], bh[Kt], acc[q], 0, 0, 0);
                acc[q] = __builtin_amdgcn_mfma_f32_16x16x32_bf16(ah[q][Kt], bl[Kt], acc[q], 0, 0, 0);
                acc[q] = __builtin_amdgcn_mfma_f32_16x16x32_bf16(al[q][Kt], bh[Kt], acc[q], 0, 0, 0);
            }
#pragma unroll
        for (int q = 0; q < 4; ++q)
            *(f32x4*)&attr[lm][(MtB + q) * 16 + lq * 4] = acc[q];
    }

    // ---- GEMM2 preload (Kt 0..3): independent of attr -> issue BEFORE the
    // barrier; softmax hides the latency. 32 VGPR held through P2.
    s16x8 pbh[4], pbl[4];
    {
        const int dcol = w * 16 + lm;
        const unsigned short* th  = seqTH + ((size_t)b * kD + dcol) * kSP;
        const unsigned short* tl_ = seqTL + ((size_t)b * kD + dcol) * kSP;
#pragma unroll
        for (int Kt = 0; Kt < 4; ++Kt) {
            pbh[Kt] = *(const s16x8*)&th[Kt * 32 + lq * 8];
            pbl[Kt] = *(const s16x8*)&tl_[Kt * 32 + lq * 8];
        }
    }
    __syncthreads();

    // ---- P2: masked softmax * dec, rows n = 4w..4w+3 -> bf16 hi/lo
    {
        bool ok0 = vm[b * kS + l] != 0;
        bool ok1 = vm[b * kS + l + 64] != 0;
        bool ok2 = vm[b * kS + l + 128] != 0;
        bool ok3 = (l < 8) && (vm[b * kS + 192 + l] != 0);
        const int s3 = (l < 8) ? 192 + l : kS - 1;
#pragma unroll
        for (int j = 0; j < 4; ++j) {
            const int n = 4 * w + j, r = n & 7;
            float a0 = ok0 ? attr[n][l]       : -INFINITY;
            float a1 = ok1 ? attr[n][l + 64]  : -INFINITY;
            float a2 = ok2 ? attr[n][l + 128] : -INFINITY;
            float a3 = ok3 ? attr[n][s3]      : -INFINITY;
            float m = fmaxf(fmaxf(a0, a1), fmaxf(a2, a3));
#pragma unroll
            for (int off = 32; off; off >>= 1) m = fmaxf(m, __shfl_xor(m, off));
            float e0 = __expf(a0 - m), e1 = __expf(a1 - m);
            float e2 = __expf(a2 - m), e3 = ok3 ? __expf(a3 - m) : 0.f;
            float ssum = e0 + e1 + e2 + e3;
#pragma unroll
            for (int off = 32; off; off >>= 1) ssum += __shfl_xor(ssum, off);
            const float inv = 1.0f / ssum;
            const float* dg = dec + ((size_t)b * kR + r) * kS;
            float p0 = e0 * inv * dg[l];
            float p1 = e1 * inv * dg[l + 64];
            float p2 = e2 * inv * dg[l + 128];
            float p3 = ok3 ? e3 * inv * dg[192 + l] : 0.f;
            float hf;
            ath[n][l]       = bf_hi(p0, hf); atl[n][l]       = bf_rne(p0 - hf);
            ath[n][l + 64]  = bf_hi(p1, hf); atl[n][l + 64]  = bf_rne(p1 - hf);
            ath[n][l + 128] = bf_hi(p2, hf); atl[n][l + 128] = bf_rne(p2 - hf);
            if (l < 32) {   // s in [192,224): real for l<8, ZERO K-pad else
                float pv = (l < 8) ? p3 : 0.f;
                ath[n][192 + l] = bf_hi(pv, hf); atl[n][192 + l] = bf_rne(pv - hf);
            }
        }
    }
    __syncthreads();

    // ---- GEMM2: context; wave w owns d-cols [16w,16w+16); K=224 via seqT.
    // Kt 0..3 from preloaded regs; Kt 4..6 issued here, overlapping MFMAs.
    {
        const int dcol = w * 16 + lm;
        const unsigned short* th  = seqTH + ((size_t)b * kD + dcol) * kSP;
        const unsigned short* tl_ = seqTL + ((size_t)b * kD + dcol) * kSP;
        s16x8 qbh[3], qbl[3];
#pragma unroll
        for (int Kt = 4; Kt < 7; ++Kt) {
            qbh[Kt - 4] = *(const s16x8*)&th[Kt * 32 + lq * 8];
            qbl[Kt - 4] = *(const s16x8*)&tl_[Kt * 32 + lq * 8];
        }
        f32x4 acc = {0.f, 0.f, 0.f, 0.f};
#pragma unroll
        for (int Kt = 0; Kt < 7; ++Kt) {
            const int s0 = Kt * 32 + lq * 8;
            s16x8 bh  = (Kt < 4) ? pbh[Kt] : qbh[Kt - 4];
            s16x8 bl  = (Kt < 4) ? pbl[Kt] : qbl[Kt - 4];
            s16x8 ahh = *(const s16x8*)&ath[lm][s0];
            s16x8 alo = *(const s16x8*)&atl[lm][s0];
            acc = __builtin_amdgcn_mfma_f32_16x16x32_bf16(ahh, bh, acc, 0, 0, 0);
            acc = __builtin_amdgcn_mfma_f32_16x16x32_bf16(ahh, bl, acc, 0, 0, 0);
            acc = __builtin_amdgcn_mfma_f32_16x16x32_bf16(alo, bh, acc, 0, 0, 0);
        }
#pragma unroll
        for (int i = 0; i < 4; ++i) {
            const int n = lq * 4 + i, tl2 = n >> 3, r = n & 7;
            out[(((size_t)(b * kT + t0 + tl2)) * kR + r) * kD + dcol] = acc[i];
        }
    }
}

extern "C" void kernel_launch(void* const* d_in, const int* in_sizes, int n_in,
                              void* d_out, int out_size, void* d_ws, size_t ws_size,
                              hipStream_t stream) {
    const float* seq    = (const float*)d_in[0];
    const float* dt     = (const float*)d_in[1];
    const float* target = (const float*)d_in[2];
    const float* tv     = (const float*)d_in[3];
    const int*   vm     = (const int*)  d_in[4];
    const float* rel    = (const float*)d_in[5];
    const float* fr     = (const float*)d_in[6];
    const float* fi     = (const float*)d_in[7];
    float* out = (float*)d_out;

    // d_ws layout (~29.4 MB; ws is poison-filled by harness regardless):
    float* dec = (float*)d_ws;                                   // 1.6 MB
    unsigned short* seqH  = (unsigned short*)((char*)d_ws + 1638400);
    unsigned short* seqL  = seqH + (size_t)kB * kS * kD;         // +6.55 MB
    unsigned short* seqTH = seqL + (size_t)kB * kS * kD;         // +6.55 MB
    unsigned short* seqTL = seqTH + (size_t)kB * kD * kSP;       // +7.34 MB

    prep_kernel<<<7 * kB, 256, 0, stream>>>(seq, dt, fr, fi, vm,
                                            dec, seqH, seqL, seqTH, seqTL);
    rda_mfma<<<kB * 4, 256, 0, stream>>>(target, tv, vm, rel, dec,
                                         seqH, seqL, seqTH, seqTL, out);
}